// Round 1
// baseline (775.215 us; speedup 1.0000x reference)
//
#include <hip/hip_runtime.h>
#include <math.h>

typedef unsigned short ushort_t;
typedef __attribute__((ext_vector_type(8))) short bf16x8;
typedef __attribute__((ext_vector_type(4))) float f32x4;

#define TOKENS   4096
#define D_DIM    1024
#define E_NUM    8
#define F_DIM    4096
#define ROWS_CAP 9216   // 8192 + 8*128 padding headroom

__device__ __forceinline__ ushort_t f2bf(float f) {
    union { float f; unsigned u; } v; v.f = f;
    unsigned r = v.u + 0x7FFFu + ((v.u >> 16) & 1u);   // RNE
    return (ushort_t)(r >> 16);
}
__device__ __forceinline__ float bf2f(ushort_t u) {
    union { unsigned u; float f; } v; v.u = ((unsigned)u) << 16;
    return v.f;
}

// ---------------- Router: logits -> top2 -> gates -> per-expert position ----
__global__ __launch_bounds__(64) void router_kernel(
    const float* __restrict__ x, const float* __restrict__ Wr,
    const float* __restrict__ br,
    int* __restrict__ cnt, int* __restrict__ tok_e, int* __restrict__ tok_pos,
    float* __restrict__ tok_gate)
{
    int t = blockIdx.x;
    int lane = threadIdx.x;
    const float* xrow = x + (size_t)t * D_DIM;
    float acc[E_NUM];
#pragma unroll
    for (int e = 0; e < E_NUM; e++) acc[e] = 0.f;
    for (int d = lane; d < D_DIM; d += 64) {
        float xv = xrow[d];
#pragma unroll
        for (int e = 0; e < E_NUM; e++)
            acc[e] += xv * Wr[e * D_DIM + d];
    }
#pragma unroll
    for (int e = 0; e < E_NUM; e++) {
        float v = acc[e];
        for (int off = 32; off > 0; off >>= 1)
            v += __shfl_down(v, off, 64);
        acc[e] = v;
    }
    if (lane == 0) {
        float lg[E_NUM];
#pragma unroll
        for (int e = 0; e < E_NUM; e++) lg[e] = acc[e] + br[e];
        int e0 = 0;
#pragma unroll
        for (int e = 1; e < E_NUM; e++) if (lg[e] > lg[e0]) e0 = e;
        int e1 = (e0 == 0) ? 1 : 0;
#pragma unroll
        for (int e = 0; e < E_NUM; e++)
            if (e != e0 && lg[e] > lg[e1]) e1 = e;
        float g1 = expf(lg[e1] - lg[e0]);
        float denom = 1.f + g1;
        float gate0 = 1.f / denom, gate1 = g1 / denom;
        int p0 = atomicAdd(&cnt[e0], 1);
        int p1 = atomicAdd(&cnt[e1], 1);
        tok_e[t * 2] = e0;     tok_pos[t * 2] = p0;     tok_gate[t * 2] = gate0;
        tok_e[t * 2 + 1] = e1; tok_pos[t * 2 + 1] = p1; tok_gate[t * 2 + 1] = gate1;
    }
}

// ---------------- Padded per-expert offsets (single thread, 8 experts) ------
__global__ void offsets_kernel(const int* __restrict__ cnt,
                               int* __restrict__ pcount, int* __restrict__ poff)
{
    if (threadIdx.x == 0 && blockIdx.x == 0) {
        int off = 0;
        for (int e = 0; e < E_NUM; e++) {
            poff[e] = off;
            int pc = (cnt[e] + 127) & ~127;
            pcount[e] = pc;
            off += pc;
        }
        poff[E_NUM] = off;
    }
}

// ---------------- Gather x rows (fp32 -> bf16) into expert-compacted Xg -----
__global__ __launch_bounds__(256) void gather_kernel(
    const float* __restrict__ x,
    const int* __restrict__ tok_e, const int* __restrict__ tok_pos,
    const float* __restrict__ tok_gate, const int* __restrict__ poff,
    ushort_t* __restrict__ Xg, float* __restrict__ grow, int* __restrict__ rowof)
{
    int idx = blockIdx.x;         // (token, k) pair, 0..8191
    int t = idx >> 1;
    int e = tok_e[idx];
    int row = poff[e] + tok_pos[idx];
    if (threadIdx.x == 0) {
        grow[row] = tok_gate[idx];
        rowof[idx] = row;
    }
    const float4* src = (const float4*)(x + (size_t)t * D_DIM);
    ushort_t* dst = Xg + (size_t)row * D_DIM;
    int i = threadIdx.x;          // 4 floats per thread
    float4 v = src[i];
    ushort4 o;
    o.x = f2bf(v.x); o.y = f2bf(v.y); o.z = f2bf(v.z); o.w = f2bf(v.w);
    *(ushort4*)(dst + i * 4) = o;
}

// ---------------- GEMM: C[m,n] = sum_k A[m,k]*B[n,k] (both K-contiguous) ----
// ACT==0: H[row,n] = bf16(silu(C + b1[e,n]))
// ACT==1: O[row,n] = bf16(grow[row] * (C + b2[e,n]))
template <int ACT>
__global__ __launch_bounds__(256) void gemm_kernel(
    const ushort_t* __restrict__ A,   // bf16 rows, ld = K
    const float* __restrict__ Bw,     // [E][N][K] fp32
    const float* __restrict__ bias,   // [E][N]
    const int* __restrict__ poff, const int* __restrict__ pcount,
    const float* __restrict__ grow,
    ushort_t* __restrict__ Cout,      // bf16 rows, ld = N
    int N, int K)
{
    const int BK = 64;
    const int LDT = 72;               // LDS stride (elems): 144 B -> only 2-way conflicts
    __shared__ ushort_t As[128 * LDT];
    __shared__ ushort_t Bs[128 * LDT];

    int e = blockIdx.z;
    int pc = pcount[e];
    int mt = blockIdx.y;
    if (mt * 128 >= pc) return;
    int rowbase = poff[e] + mt * 128;
    int nbase = blockIdx.x * 128;

    int tid = threadIdx.x;
    int wave = tid >> 6;
    int lane = tid & 63;
    int wm = (wave & 1) * 64;
    int wn = (wave >> 1) * 64;
    int quad = lane >> 4;
    int l16 = lane & 15;

    f32x4 acc[4][4];
#pragma unroll
    for (int i = 0; i < 4; i++)
#pragma unroll
        for (int j = 0; j < 4; j++) {
            f32x4 z = {0.f, 0.f, 0.f, 0.f};
            acc[i][j] = z;
        }

    const ushort_t* Arow = A + (size_t)rowbase * K;
    const float* Brow = Bw + (size_t)e * N * K + (size_t)nbase * K;

    for (int k0 = 0; k0 < K; k0 += BK) {
        __syncthreads();
        // stage A: 128 rows x 64 bf16 ; 1024 chunks of 8 elems, 4 per thread
#pragma unroll
        for (int it = 0; it < 4; it++) {
            int id = it * 256 + tid;
            int row = id >> 3;
            int chunk = id & 7;
            uint4 v = *(const uint4*)(Arow + (size_t)row * K + k0 + chunk * 8);
            *(uint4*)&As[row * LDT + chunk * 8] = v;
        }
        // stage B: 128 rows x 64 fp32 -> bf16
#pragma unroll
        for (int it = 0; it < 4; it++) {
            int id = it * 256 + tid;
            int row = id >> 3;
            int chunk = id & 7;
            const float4* p = (const float4*)(Brow + (size_t)row * K + k0 + chunk * 8);
            float4 f0 = p[0], f1 = p[1];
            union { ushort_t u[8]; uint4 v; } tmp;
            tmp.u[0] = f2bf(f0.x); tmp.u[1] = f2bf(f0.y);
            tmp.u[2] = f2bf(f0.z); tmp.u[3] = f2bf(f0.w);
            tmp.u[4] = f2bf(f1.x); tmp.u[5] = f2bf(f1.y);
            tmp.u[6] = f2bf(f1.z); tmp.u[7] = f2bf(f1.w);
            *(uint4*)&Bs[row * LDT + chunk * 8] = tmp.v;
        }
        __syncthreads();
#pragma unroll
        for (int kk = 0; kk < BK; kk += 32) {
            bf16x8 af[4], bfr[4];
#pragma unroll
            for (int i = 0; i < 4; i++)
                af[i] = *(const bf16x8*)&As[(wm + i * 16 + l16) * LDT + kk + quad * 8];
#pragma unroll
            for (int j = 0; j < 4; j++)
                bfr[j] = *(const bf16x8*)&Bs[(wn + j * 16 + l16) * LDT + kk + quad * 8];
#pragma unroll
            for (int i = 0; i < 4; i++)
#pragma unroll
                for (int j = 0; j < 4; j++)
                    acc[i][j] = __builtin_amdgcn_mfma_f32_16x16x32_bf16(
                        af[i], bfr[j], acc[i][j], 0, 0, 0);
        }
    }

    // epilogue: D[m = quad*4+r (per 16-tile)][n = lane&15]
#pragma unroll
    for (int i = 0; i < 4; i++) {
#pragma unroll
        for (int j = 0; j < 4; j++) {
            int n = nbase + wn + j * 16 + l16;
            float bv = bias[(size_t)e * N + n];
#pragma unroll
            for (int r = 0; r < 4; r++) {
                int grow_row = rowbase + wm + i * 16 + quad * 4 + r;
                float v = acc[i][j][r] + bv;
                if (ACT == 0) {
                    v = v / (1.f + __expf(-v));           // SiLU
                } else {
                    v = grow[grow_row] * v;               // gate scale
                }
                Cout[(size_t)grow_row * N + n] = f2bf(v);
            }
        }
    }
}

// ---------------- Combine: y[t] = O[row0] + O[row1] -------------------------
__global__ __launch_bounds__(256) void combine_kernel(
    const ushort_t* __restrict__ O, const int* __restrict__ rowof,
    float* __restrict__ y)
{
    int t = blockIdx.x;
    int r0 = rowof[t * 2], r1 = rowof[t * 2 + 1];
    int d = threadIdx.x * 4;
    ushort4 a = *(const ushort4*)&O[(size_t)r0 * D_DIM + d];
    ushort4 b = *(const ushort4*)&O[(size_t)r1 * D_DIM + d];
    float4 o;
    o.x = bf2f(a.x) + bf2f(b.x);
    o.y = bf2f(a.y) + bf2f(b.y);
    o.z = bf2f(a.z) + bf2f(b.z);
    o.w = bf2f(a.w) + bf2f(b.w);
    *(float4*)&y[(size_t)t * D_DIM + d] = o;
}

extern "C" void kernel_launch(void* const* d_in, const int* in_sizes, int n_in,
                              void* d_out, int out_size, void* d_ws, size_t ws_size,
                              hipStream_t stream)
{
    (void)in_sizes; (void)n_in; (void)out_size; (void)ws_size;
    const float* x  = (const float*)d_in[0];
    const float* Wr = (const float*)d_in[1];
    const float* br = (const float*)d_in[2];
    const float* W1 = (const float*)d_in[3];
    const float* b1 = (const float*)d_in[4];
    const float* W2 = (const float*)d_in[5];
    const float* b2 = (const float*)d_in[6];
    float* y = (float*)d_out;

    char* ws = (char*)d_ws;
    int*   cnt      = (int*)(ws + 0);        // 8 ints
    int*   pcount   = (int*)(ws + 32);       // 8 ints
    int*   poff     = (int*)(ws + 64);       // 9 ints
    int*   tok_e    = (int*)(ws + 128);                    // 8192
    int*   tok_pos  = (int*)(ws + 128 + 32768);            // 8192
    float* tok_gate = (float*)(ws + 128 + 65536);          // 8192
    int*   rowof    = (int*)(ws + 128 + 98304);            // 8192
    float* grow     = (float*)(ws + 128 + 131072);         // 9216 floats
    ushort_t* Xg = (ushort_t*)(ws + 168064);                       // 9216x1024 bf16
    ushort_t* H  = (ushort_t*)(ws + 168064 + 18874368ull);         // 9216x4096 bf16
    ushort_t* O  = (ushort_t*)(ws + 168064 + 18874368ull + 75497472ull); // 9216x1024 bf16

    hipMemsetAsync(cnt, 0, 32, stream);
    hipMemsetAsync(Xg, 0, 18874368ull, stream);   // zero pad rows

    router_kernel<<<TOKENS, 64, 0, stream>>>(x, Wr, br, cnt, tok_e, tok_pos, tok_gate);
    offsets_kernel<<<1, 64, 0, stream>>>(cnt, pcount, poff);
    gather_kernel<<<TOKENS * 2, 256, 0, stream>>>(x, tok_e, tok_pos, tok_gate, poff,
                                                  Xg, grow, rowof);
    // GEMM1: [rows x 1024] @ W1[e]^T -> silu -> H [rows x 4096]
    gemm_kernel<0><<<dim3(F_DIM / 128, 32, E_NUM), 256, 0, stream>>>(
        Xg, W1, b1, poff, pcount, nullptr, H, F_DIM, D_DIM);
    // GEMM2: [rows x 4096] @ W2[e]^T -> gate scale -> O [rows x 1024]
    gemm_kernel<1><<<dim3(D_DIM / 128, 32, E_NUM), 256, 0, stream>>>(
        H, W2, b2, poff, pcount, grow, O, D_DIM, F_DIM);
    combine_kernel<<<TOKENS, 256, 0, stream>>>(O, rowof, y);
}

// Round 2
// 667.137 us; speedup vs baseline: 1.1620x; 1.1620x over previous
//
#include <hip/hip_runtime.h>
#include <math.h>

typedef unsigned short ushort_t;
typedef __attribute__((ext_vector_type(8))) short bf16x8;
typedef __attribute__((ext_vector_type(4))) float f32x4;

#define TOKENS   4096
#define D_DIM    1024
#define E_NUM    8
#define F_DIM    4096

#define GLDS16(gp, lp) __builtin_amdgcn_global_load_lds( \
    (const __attribute__((address_space(1))) unsigned int*)(gp), \
    (__attribute__((address_space(3))) unsigned int*)(lp), 16, 0, 0)

__device__ __forceinline__ ushort_t f2bf(float f) {
    union { float f; unsigned u; } v; v.f = f;
    unsigned r = v.u + 0x7FFFu + ((v.u >> 16) & 1u);   // RNE
    return (ushort_t)(r >> 16);
}
__device__ __forceinline__ float bf2f(ushort_t u) {
    union { unsigned u; float f; } v; v.u = ((unsigned)u) << 16;
    return v.f;
}

// ---------------- fp32 -> bf16 bulk convert (8 elems/thread) ----------------
__global__ __launch_bounds__(256) void convert_kernel(
    const float* __restrict__ src, ushort_t* __restrict__ dst)
{
    size_t i = ((size_t)blockIdx.x * 256 + threadIdx.x) * 8;
    float4 a = *(const float4*)(src + i);
    float4 b = *(const float4*)(src + i + 4);
    union { ushort_t u[8]; uint4 v; } t;
    t.u[0] = f2bf(a.x); t.u[1] = f2bf(a.y); t.u[2] = f2bf(a.z); t.u[3] = f2bf(a.w);
    t.u[4] = f2bf(b.x); t.u[5] = f2bf(b.y); t.u[6] = f2bf(b.z); t.u[7] = f2bf(b.w);
    *(uint4*)(dst + i) = t.v;
}

// ---------------- Router: logits -> top2 -> gates -> per-expert position ----
__global__ __launch_bounds__(64) void router_kernel(
    const float* __restrict__ x, const float* __restrict__ Wr,
    const float* __restrict__ br,
    int* __restrict__ cnt, int* __restrict__ tok_e, int* __restrict__ tok_pos,
    float* __restrict__ tok_gate)
{
    int t = blockIdx.x;
    int lane = threadIdx.x;
    const float* xrow = x + (size_t)t * D_DIM;
    float acc[E_NUM];
#pragma unroll
    for (int e = 0; e < E_NUM; e++) acc[e] = 0.f;
    for (int d = lane; d < D_DIM; d += 64) {
        float xv = xrow[d];
#pragma unroll
        for (int e = 0; e < E_NUM; e++)
            acc[e] += xv * Wr[e * D_DIM + d];
    }
#pragma unroll
    for (int e = 0; e < E_NUM; e++) {
        float v = acc[e];
        for (int off = 32; off > 0; off >>= 1)
            v += __shfl_down(v, off, 64);
        acc[e] = v;
    }
    if (lane == 0) {
        float lg[E_NUM];
#pragma unroll
        for (int e = 0; e < E_NUM; e++) lg[e] = acc[e] + br[e];
        int e0 = 0;
#pragma unroll
        for (int e = 1; e < E_NUM; e++) if (lg[e] > lg[e0]) e0 = e;
        int e1 = (e0 == 0) ? 1 : 0;
#pragma unroll
        for (int e = 0; e < E_NUM; e++)
            if (e != e0 && lg[e] > lg[e1]) e1 = e;
        float g1 = expf(lg[e1] - lg[e0]);
        float denom = 1.f + g1;
        float gate0 = 1.f / denom, gate1 = g1 / denom;
        int p0 = atomicAdd(&cnt[e0], 1);
        int p1 = atomicAdd(&cnt[e1], 1);
        tok_e[t * 2] = e0;     tok_pos[t * 2] = p0;     tok_gate[t * 2] = gate0;
        tok_e[t * 2 + 1] = e1; tok_pos[t * 2 + 1] = p1; tok_gate[t * 2 + 1] = gate1;
    }
}

// ---------------- Padded per-expert offsets ---------------------------------
__global__ void offsets_kernel(const int* __restrict__ cnt,
                               int* __restrict__ pcount, int* __restrict__ poff)
{
    if (threadIdx.x == 0 && blockIdx.x == 0) {
        int off = 0;
        for (int e = 0; e < E_NUM; e++) {
            poff[e] = off;
            int pc = (cnt[e] + 127) & ~127;
            pcount[e] = pc;
            off += pc;
        }
        poff[E_NUM] = off;
    }
}

// ---------------- Gather x rows (fp32 -> bf16) into expert-compacted Xg -----
__global__ __launch_bounds__(256) void gather_kernel(
    const float* __restrict__ x,
    const int* __restrict__ tok_e, const int* __restrict__ tok_pos,
    const float* __restrict__ tok_gate, const int* __restrict__ poff,
    ushort_t* __restrict__ Xg, float* __restrict__ grow, int* __restrict__ rowof)
{
    int idx = blockIdx.x;         // (token, k) pair, 0..8191
    int t = idx >> 1;
    int e = tok_e[idx];
    int row = poff[e] + tok_pos[idx];
    if (threadIdx.x == 0) {
        grow[row] = tok_gate[idx];
        rowof[idx] = row;
    }
    const float4* src = (const float4*)(x + (size_t)t * D_DIM);
    ushort_t* dst = Xg + (size_t)row * D_DIM;
    int i = threadIdx.x;          // 4 floats per thread
    float4 v = src[i];
    ushort4 o;
    o.x = f2bf(v.x); o.y = f2bf(v.y); o.z = f2bf(v.z); o.w = f2bf(v.w);
    *(ushort4*)(dst + i * 4) = o;
}

// ---------------- GEMM: C[m,n] = sum_k A[m,k]*B[n,k] (bf16, glds staging) ---
// LDS layout is XOR-swizzled at the SOURCE: phys chunk c of row r holds global
// chunk c ^ (r&7). glds dest = wave-uniform base + lane*16 (m104/m108), so the
// swizzle must live in the global address, not the LDS address.
// ACT==0: H[row,n] = bf16(silu(C + b1[e,n]))
// ACT==1: O[row,n] = bf16(grow[row] * (C + b2[e,n]))
template <int ACT>
__global__ __launch_bounds__(256, 4) void gemm_kernel(
    const ushort_t* __restrict__ A,   // bf16 rows, ld = K
    const ushort_t* __restrict__ Bw,  // [E][N][K] bf16
    const float* __restrict__ bias,   // [E][N]
    const int* __restrict__ poff, const int* __restrict__ pcount,
    const float* __restrict__ grow,
    ushort_t* __restrict__ Cout,      // bf16 rows, ld = N
    int N, int K)
{
    __shared__ ushort_t As[128 * 64];
    __shared__ ushort_t Bs[128 * 64];

    int e = blockIdx.z;
    int pc = pcount[e];
    int mt = blockIdx.y;
    if (mt * 128 >= pc) return;
    int rowbase = poff[e] + mt * 128;
    int nbase = blockIdx.x * 128;

    int tid = threadIdx.x;
    int wave = tid >> 6;
    int lane = tid & 63;
    int wm = (wave & 1) * 64;
    int wn = (wave >> 1) * 64;
    int quad = lane >> 4;
    int l16 = lane & 15;
    int fswz = l16 & 7;               // fragment-read swizzle key

    int srow = lane >> 3;             // 0..7 within an 8-row group
    int soff = ((lane & 7) ^ srow) * 8;  // swizzled source chunk (elems)

    f32x4 acc[4][4];
#pragma unroll
    for (int i = 0; i < 4; i++)
#pragma unroll
        for (int j = 0; j < 4; j++) {
            f32x4 z = {0.f, 0.f, 0.f, 0.f};
            acc[i][j] = z;
        }

    const ushort_t* Ag = A + (size_t)rowbase * K;
    const ushort_t* Bg = Bw + ((size_t)e * N + nbase) * K;

    for (int k0 = 0; k0 < K; k0 += 64) {
        __syncthreads();
#pragma unroll
        for (int it = 0; it < 4; it++) {
            int r = wave * 32 + it * 8;   // wave-uniform base row of 8-row group
            GLDS16(Ag + (size_t)(r + srow) * K + k0 + soff, &As[r * 64]);
            GLDS16(Bg + (size_t)(r + srow) * K + k0 + soff, &Bs[r * 64]);
        }
        __syncthreads();   // drains vmcnt(0) -> glds data visible
#pragma unroll
        for (int kk = 0; kk < 64; kk += 32) {
            int kc = kk >> 3;             // logical chunk base: 0 or 4
            bf16x8 af[4], bfr[4];
#pragma unroll
            for (int i = 0; i < 4; i++)
                af[i] = *(const bf16x8*)&As[(wm + i * 16 + l16) * 64 +
                                            (((quad + kc) ^ fswz) << 3)];
#pragma unroll
            for (int j = 0; j < 4; j++)
                bfr[j] = *(const bf16x8*)&Bs[(wn + j * 16 + l16) * 64 +
                                             (((quad + kc) ^ fswz) << 3)];
#pragma unroll
            for (int i = 0; i < 4; i++)
#pragma unroll
                for (int j = 0; j < 4; j++)
                    acc[i][j] = __builtin_amdgcn_mfma_f32_16x16x32_bf16(
                        af[i], bfr[j], acc[i][j], 0, 0, 0);
        }
    }

    // epilogue: D row = quad*4+r within 16-tile, col = l16
#pragma unroll
    for (int i = 0; i < 4; i++) {
#pragma unroll
        for (int j = 0; j < 4; j++) {
            int n = nbase + wn + j * 16 + l16;
            float bv = bias[(size_t)e * N + n];
#pragma unroll
            for (int r = 0; r < 4; r++) {
                int grow_row = rowbase + wm + i * 16 + quad * 4 + r;
                float v = acc[i][j][r] + bv;
                if (ACT == 0) {
                    v = v / (1.f + __expf(-v));           // SiLU
                } else {
                    v = grow[grow_row] * v;               // gate scale
                }
                Cout[(size_t)grow_row * N + n] = f2bf(v);
            }
        }
    }
}

// ---------------- Combine: y[t] = O[row0] + O[row1] -------------------------
__global__ __launch_bounds__(256) void combine_kernel(
    const ushort_t* __restrict__ O, const int* __restrict__ rowof,
    float* __restrict__ y)
{
    int t = blockIdx.x;
    int r0 = rowof[t * 2], r1 = rowof[t * 2 + 1];
    int d = threadIdx.x * 4;
    ushort4 a = *(const ushort4*)&O[(size_t)r0 * D_DIM + d];
    ushort4 b = *(const ushort4*)&O[(size_t)r1 * D_DIM + d];
    float4 o;
    o.x = bf2f(a.x) + bf2f(b.x);
    o.y = bf2f(a.y) + bf2f(b.y);
    o.z = bf2f(a.z) + bf2f(b.z);
    o.w = bf2f(a.w) + bf2f(b.w);
    *(float4*)&y[(size_t)t * D_DIM + d] = o;
}

extern "C" void kernel_launch(void* const* d_in, const int* in_sizes, int n_in,
                              void* d_out, int out_size, void* d_ws, size_t ws_size,
                              hipStream_t stream)
{
    (void)in_sizes; (void)n_in; (void)out_size; (void)ws_size;
    const float* x  = (const float*)d_in[0];
    const float* Wr = (const float*)d_in[1];
    const float* br = (const float*)d_in[2];
    const float* W1 = (const float*)d_in[3];
    const float* b1 = (const float*)d_in[4];
    const float* W2 = (const float*)d_in[5];
    const float* b2 = (const float*)d_in[6];
    float* y = (float*)d_out;

    char* ws = (char*)d_ws;
    int*   cnt      = (int*)(ws + 0);        // 8 ints
    int*   pcount   = (int*)(ws + 32);       // 8 ints
    int*   poff     = (int*)(ws + 64);       // 9 ints
    int*   tok_e    = (int*)(ws + 128);      // 8192 ints
    int*   tok_pos  = (int*)(ws + 32896);    // 8192 ints
    float* tok_gate = (float*)(ws + 65664);  // 8192 floats
    int*   rowof    = (int*)(ws + 98432);    // 8192 ints
    float* grow     = (float*)(ws + 131200); // 9216 floats
    // big buffers (256 KiB aligned start)
    ushort_t* Xg = (ushort_t*)(ws + 262144);                 // 9216x1024 bf16 (18,874,368 B)
    ushort_t* O  = Xg;                                       // aliased: Xg dead after GEMM1
    ushort_t* H  = (ushort_t*)(ws + 262144 + 18874368ull);   // 9216x4096 bf16 (75,497,472 B)
    ushort_t* Wb = (ushort_t*)(ws + 262144 + 18874368ull + 75497472ull); // 67,108,864 B, reused W1 then W2

    hipMemsetAsync(cnt, 0, 32, stream);
    hipMemsetAsync(Xg, 0, 18874368ull, stream);   // zero pad rows of Xg

    router_kernel<<<TOKENS, 64, 0, stream>>>(x, Wr, br, cnt, tok_e, tok_pos, tok_gate);
    offsets_kernel<<<1, 64, 0, stream>>>(cnt, pcount, poff);
    gather_kernel<<<TOKENS * 2, 256, 0, stream>>>(x, tok_e, tok_pos, tok_gate, poff,
                                                  Xg, grow, rowof);
    // W1 -> bf16, then GEMM1: [rows x 1024] @ W1[e]^T -> silu -> H [rows x 4096]
    convert_kernel<<<16384, 256, 0, stream>>>(W1, Wb);
    gemm_kernel<0><<<dim3(F_DIM / 128, 32, E_NUM), 256, 0, stream>>>(
        Xg, Wb, b1, poff, pcount, nullptr, H, F_DIM, D_DIM);
    // W2 -> bf16 (same buffer), then GEMM2: [rows x 4096] @ W2[e]^T -> gate -> O
    convert_kernel<<<16384, 256, 0, stream>>>(W2, Wb);
    gemm_kernel<1><<<dim3(D_DIM / 128, 32, E_NUM), 256, 0, stream>>>(
        H, Wb, b2, poff, pcount, grow, O, D_DIM, F_DIM);
    combine_kernel<<<TOKENS, 256, 0, stream>>>(O, rowof, y);
}